// Round 15
// baseline (119.512 us; speedup 1.0000x reference)
//
#include <hip/hip_runtime.h>
#include <hip/hip_bf16.h>
#include <math.h>

typedef short short8  __attribute__((ext_vector_type(8)));
typedef float floatx4 __attribute__((ext_vector_type(4)));
typedef char  charx8  __attribute__((ext_vector_type(8)));
typedef int   intx4   __attribute__((ext_vector_type(4)));

#define NX 8192
#define NY 8192
#define KD 512
#define QS 26.0f                   // i8 quant scale
#define INV_QS2 (1.0f / (26.0f * 26.0f))
#define BM 128
#define BN 256
#define BK 64                      // bytes per row per K-tile (i8)

// ---- order-preserving float<->uint transform for atomicMax on floats ----
__device__ inline unsigned int f2u_ord(float x) {
    unsigned int u = __float_as_uint(x);
    return (u & 0x80000000u) ? ~u : (u | 0x80000000u);
}
__device__ inline float u2f_ord(unsigned int u) {
    return (u & 0x80000000u) ? __uint_as_float(u & 0x7fffffffu)
                             : __uint_as_float(~u);
}

__device__ inline char q8(float x) {
    float xs = fmaxf(-127.0f, fminf(127.0f, x * QS));
    return (char)(int)rintf(xs);
}
__device__ inline charx8 qpack8(const float4 u, const float4 v) {
    charx8 r;
    r[0] = q8(u.x); r[1] = q8(u.y); r[2] = q8(u.z); r[3] = q8(u.w);
    r[4] = q8(v.x); r[5] = q8(v.y); r[6] = q8(v.z); r[7] = q8(v.w);
    return r;
}

__device__ __forceinline__ void gload_lds16(const void* g, void* l) {
    __builtin_amdgcn_global_load_lds(
        (const __attribute__((address_space(1))) unsigned int*)g,
        (__attribute__((address_space(3))) unsigned int*)l, 16, 0, 0);
}

// ================= kernel 0: f32 -> i8 quantize + inv-norms + rowmax init ===
__global__ __launch_bounds__(256) void convert_kernel(
    const float* __restrict__ ex, const float* __restrict__ ey,
    char* __restrict__ exq, char* __restrict__ eyq,
    float* __restrict__ inv_nx, float* __restrict__ inv_ny,
    unsigned int* __restrict__ rowmax_u) {
    const int tid  = threadIdx.x;
    const int wid  = tid >> 6, lane = tid & 63;
    const int gr   = blockIdx.x * 4 + wid;          // 0..16383

    const bool isx = (gr < NX);
    const int row  = isx ? gr : gr - NX;
    const float* src = isx ? ex : ey;
    char* dst        = isx ? exq : eyq;
    float* inv       = isx ? inv_nx : inv_ny;

    const float4* p = reinterpret_cast<const float4*>(src + (size_t)row * KD) + lane * 2;
    float4 v0 = p[0], v1 = p[1];
    *reinterpret_cast<charx8*>(dst + (size_t)row * KD + lane * 8) = qpack8(v0, v1);

    float s = v0.x*v0.x + v0.y*v0.y + v0.z*v0.z + v0.w*v0.w
            + v1.x*v1.x + v1.y*v1.y + v1.z*v1.z + v1.w*v1.w;
    #pragma unroll
    for (int off = 32; off; off >>= 1) s += __shfl_xor(s, off);
    if (lane == 0) {
        inv[row] = 1.0f / sqrtf(s);
        if (isx) rowmax_u[row] = 0u;    // below transform of any real float
    }
}

// ================= kernel 1: 128x256 i8 GEMM, A->regs, B->LDS (rnd-8 sync) ==
// Round-8 geometry held fixed (8 waves 2Mx4N, 128x256, 2-buf B, absolute
// vmcnt(0)+barrier per K-tile, 16 waves/CU); ONLY A's path changes:
// global->VGPR normal loads, double-buffered. Waves sharing wr read
// identical A addresses -> L1 serves the 4x reuse. Per-block-K-tile LDS
// traffic 88 KB -> 48 KB: LDS pipe (~565 cyc) drops below MFMA (~1306).
__global__ __launch_bounds__(512, 2) void gemm_i8_kernel(
    const char* __restrict__ exq, const char* __restrict__ eyq,
    const float* __restrict__ inv_ny, unsigned int* __restrict__ rowmax_u) {
    __shared__ char Bs[2][BN * BK];   // 2 x 16 KB
    __shared__ float red[BM][4];      // cross-wave-col row-max reduce

    const int tid   = threadIdx.x;
    const int lane  = tid & 63;
    const int wid   = tid >> 6;     // 0..7
    const int wr    = wid >> 2;     // 0..1 (M)
    const int wc    = wid & 3;      // 0..3 (N)
    const int g     = lane >> 4;    // 0..3
    const int rlane = lane & 15;
    const int m0    = blockIdx.x * BM;
    const int n0    = blockIdx.y * BN;

    // B staging map: 512 threads x 16 B = 8 KB = 128 rows of 64 B per issue
    const int sr  = tid >> 2;              // 0..127 row within issue
    const int sc  = tid & 3;               // chunk 0..3
    const int scs = sc ^ ((sr >> 1) & 3);  // pre-swizzled global source chunk

    // hoisted B LDS read offsets ((row>>1)&3 == (rlane>>1)&3 for all rows)
    const int gx = ((g ^ ((rlane >> 1) & 3)) << 4);
    int boff[4];
    #pragma unroll
    for (int ni = 0; ni < 4; ni++) boff[ni] = (wc * 64 + ni * 16 + rlane) * BK + gx;

    // A fragment global bases: row m0 + wr*64 + ai*16 + rlane, bytes g*16
    const char* pA[4];
    #pragma unroll
    for (int ai = 0; ai < 4; ai++)
        pA[ai] = exq + (size_t)(m0 + wr * 64 + ai * 16 + rlane) * KD + g * 16;

    intx4 acc[4][4];
    #pragma unroll
    for (int i = 0; i < 4; i++)
        #pragma unroll
        for (int j = 0; j < 4; j++)
            acc[i][j] = (intx4){0, 0, 0, 0};

    const char* gB0 = eyq + (size_t)(n0 + sr) * KD + (scs << 4);
    const char* gB1 = gB0 + (size_t)128 * KD;

    auto stageB = [&](int t, int buf) {
        gload_lds16(gB0 + (t << 6), &Bs[buf][tid * 16]);
        gload_lds16(gB1 + (t << 6), &Bs[buf][8192 + tid * 16]);
    };

    // prologue: A(0) into registers (normal loads), stage B(0)
    intx4 afC[4], afN[4];
    #pragma unroll
    for (int ai = 0; ai < 4; ai++)
        afC[ai] = *reinterpret_cast<const intx4*>(pA[ai]);
    stageB(0, 0);

    #pragma unroll
    for (int t = 0; t < 8; ++t) {           // KD/BK = 8 K-tiles
        // absolute drain (round-8 proven): B(t) fully in LDS for every wave.
        asm volatile("s_waitcnt vmcnt(0)" ::: "memory");
        __builtin_amdgcn_s_barrier();

        if (t < 7) {
            // prefetch A(t+1) (compiler guards the uses) and stage B(t+1)
            // into the other buffer (its readers finished before the barrier)
            #pragma unroll
            for (int ai = 0; ai < 4; ai++)
                afN[ai] = *reinterpret_cast<const intx4*>(pA[ai] + ((t + 1) << 6));
            stageB(t + 1, (t + 1) & 1);
        }

        intx4 bf[4];
        #pragma unroll
        for (int ni = 0; ni < 4; ni++)
            bf[ni] = *reinterpret_cast<const intx4*>(&Bs[t & 1][boff[ni]]);

        __builtin_amdgcn_s_setprio(1);
        #pragma unroll
        for (int ai = 0; ai < 4; ai++)
            #pragma unroll
            for (int ni = 0; ni < 4; ni++)
                acc[ai][ni] = __builtin_amdgcn_mfma_i32_16x16x64_i8(
                    afC[ai], bf[ni], acc[ai][ni], 0, 0, 0);
        __builtin_amdgcn_s_setprio(0);

        if (t < 7) {
            #pragma unroll
            for (int ai = 0; ai < 4; ai++) afC[ai] = afN[ai];
        }
    }

    // ---- epilogue: per-row max over this block's 256 columns ----
    float iny[4];
    #pragma unroll
    for (int ni = 0; ni < 4; ni++)
        iny[ni] = inv_ny[n0 + wc * 64 + ni * 16 + rlane] * INV_QS2;

    #pragma unroll
    for (int ai = 0; ai < 4; ai++) {
        #pragma unroll
        for (int reg = 0; reg < 4; reg++) {
            float v = -INFINITY;
            #pragma unroll
            for (int ni = 0; ni < 4; ni++)
                v = fmaxf(v, (float)acc[ai][ni][reg] * iny[ni]);
            v = fmaxf(v, __shfl_xor(v, 1));
            v = fmaxf(v, __shfl_xor(v, 2));
            v = fmaxf(v, __shfl_xor(v, 4));
            v = fmaxf(v, __shfl_xor(v, 8));
            if (rlane == 0)
                red[wr * 64 + ai * 16 + g * 4 + reg][wc] = v;
        }
    }
    __syncthreads();
    if (tid < BM) {
        float m = fmaxf(fmaxf(red[tid][0], red[tid][1]),
                        fmaxf(red[tid][2], red[tid][3]));
        atomicMax(rowmax_u + m0 + tid, f2u_ord(m));
    }
}

// ================= fallback path (f32-direct, used only if ws too small) ====
__device__ inline short bfbits(float x) {
    __hip_bfloat16 h = __float2bfloat16(x);
    return __builtin_bit_cast(short, h);
}
__device__ inline short8 pack8(const float4 u, const float4 v) {
    short8 r;
    r[0] = bfbits(u.x); r[1] = bfbits(u.y); r[2] = bfbits(u.z); r[3] = bfbits(u.w);
    r[4] = bfbits(v.x); r[5] = bfbits(v.y); r[6] = bfbits(v.z); r[7] = bfbits(v.w);
    return r;
}

__global__ __launch_bounds__(256) void prep_kernel(
    const float* __restrict__ ex, const float* __restrict__ ey,
    float* __restrict__ inv_nx, float* __restrict__ inv_ny,
    unsigned int* __restrict__ rowmax_u) {
    const int tid  = threadIdx.x;
    const int wave = tid >> 6, lane = tid & 63;
    const int row  = blockIdx.x * 4 + wave;
    if (blockIdx.y == 0) {
        int idx = blockIdx.x * 256 + tid;
        if (idx < NX) rowmax_u[idx] = 0u;
    }
    const float* src = (blockIdx.y == 0) ? ex : ey;
    float* dst       = (blockIdx.y == 0) ? inv_nx : inv_ny;
    const float4* p = reinterpret_cast<const float4*>(src + (size_t)row * KD) + lane * 2;
    float4 v0 = p[0], v1 = p[1];
    float s = v0.x*v0.x + v0.y*v0.y + v0.z*v0.z + v0.w*v0.w
            + v1.x*v1.x + v1.y*v1.y + v1.z*v1.z + v1.w*v1.w;
    #pragma unroll
    for (int off = 32; off; off >>= 1) s += __shfl_xor(s, off);
    if (lane == 0) dst[row] = 1.0f / sqrtf(s);
}

__global__ __launch_bounds__(256) void gemmmax_f32_kernel(
    const float* __restrict__ ex, const float* __restrict__ ey,
    const float* __restrict__ inv_ny, unsigned int* __restrict__ rowmax_u) {
    __shared__ short Asf[128 * 32];
    __shared__ short Bsf[128 * 32];
    const int tid  = threadIdx.x;
    const int lane = tid & 63;
    const int wid  = tid >> 6;
    const int wr   = wid >> 1, wc = wid & 1;
    const int m0   = blockIdx.x * 128;
    const int n0   = blockIdx.y * 128;
    const int srow = tid >> 1;
    const int sseg = tid & 1;
    const int sfz  = ((srow >> 1) & 3) << 4;

    floatx4 acc[4][4];
    #pragma unroll
    for (int mi = 0; mi < 4; mi++)
        #pragma unroll
        for (int ni = 0; ni < 4; ni++)
            acc[mi][ni] = (floatx4){0.f, 0.f, 0.f, 0.f};
    const int ksub  = lane >> 4;
    const int rlane = lane & 15;

    for (int k0 = 0; k0 < KD; k0 += 32) {
        const float4* ga = reinterpret_cast<const float4*>(
            ex + (size_t)(m0 + srow) * KD + k0 + sseg * 16);
        const float4* gb = reinterpret_cast<const float4*>(
            ey + (size_t)(n0 + srow) * KD + k0 + sseg * 16);
        float4 a0 = ga[0], a1 = ga[1], a2 = ga[2], a3 = ga[3];
        float4 b0 = gb[0], b1 = gb[1], b2 = gb[2], b3 = gb[3];
        __syncthreads();
        {
            char* ab = (char*)Asf + srow * 64;
            char* bb = (char*)Bsf + srow * 64;
            *reinterpret_cast<short8*>(ab + ((sseg * 32     ) ^ sfz)) = pack8(a0, a1);
            *reinterpret_cast<short8*>(ab + ((sseg * 32 + 16) ^ sfz)) = pack8(a2, a3);
            *reinterpret_cast<short8*>(bb + ((sseg * 32     ) ^ sfz)) = pack8(b0, b1);
            *reinterpret_cast<short8*>(bb + ((sseg * 32 + 16) ^ sfz)) = pack8(b2, b3);
        }
        __syncthreads();
        short8 afrag[4], bfrag[4];
        #pragma unroll
        for (int mi = 0; mi < 4; mi++) {
            int row = wr * 64 + mi * 16 + rlane;
            int fz  = ((row >> 1) & 3) << 4;
            afrag[mi] = *reinterpret_cast<const short8*>(
                (const char*)Asf + row * 64 + ((ksub * 16) ^ fz));
        }
        #pragma unroll
        for (int ni = 0; ni < 4; ni++) {
            int col = wc * 64 + ni * 16 + rlane;
            int fz  = ((col >> 1) & 3) << 4;
            bfrag[ni] = *reinterpret_cast<const short8*>(
                (const char*)Bsf + col * 64 + ((ksub * 16) ^ fz));
        }
        #pragma unroll
        for (int mi = 0; mi < 4; mi++)
            #pragma unroll
            for (int ni = 0; ni < 4; ni++)
                acc[mi][ni] = __builtin_amdgcn_mfma_f32_16x16x32_bf16(
                    afrag[mi], bfrag[ni], acc[mi][ni], 0, 0, 0);
    }
    float iny[4];
    #pragma unroll
    for (int ni = 0; ni < 4; ni++)
        iny[ni] = inv_ny[n0 + wc * 64 + ni * 16 + rlane];
    #pragma unroll
    for (int mi = 0; mi < 4; mi++) {
        #pragma unroll
        for (int reg = 0; reg < 4; reg++) {
            float v = -INFINITY;
            #pragma unroll
            for (int ni = 0; ni < 4; ni++)
                v = fmaxf(v, acc[mi][ni][reg] * iny[ni]);
            v = fmaxf(v, __shfl_xor(v, 1));
            v = fmaxf(v, __shfl_xor(v, 2));
            v = fmaxf(v, __shfl_xor(v, 4));
            v = fmaxf(v, __shfl_xor(v, 8));
            if (rlane == 0) {
                int row = m0 + wr * 64 + mi * 16 + ksub * 4 + reg;
                atomicMax(rowmax_u + row, f2u_ord(v));
            }
        }
    }
}

// ================= kernel 2: cmax -> HalfNormal log-prob -> sum =============
__global__ __launch_bounds__(1024) void finalize_kernel(
    const unsigned int* __restrict__ rowmax_u, const float* __restrict__ inv_nx,
    float* __restrict__ out) {
    __shared__ float red[16];
    const int tid = threadIdx.x;
    float s = 0.f;
    for (int i = tid; i < NX; i += 1024) {
        float cmax = u2f_ord(rowmax_u[i]) * inv_nx[i];
        float x = 1.0f - cmax;
        s += x * x;
    }
    #pragma unroll
    for (int off = 32; off; off >>= 1) s += __shfl_xor(s, off);
    if ((tid & 63) == 0) red[tid >> 6] = s;
    __syncthreads();
    if (tid < 16) {
        float t = red[tid];
        t += __shfl_xor(t, 8);
        t += __shfl_xor(t, 4);
        t += __shfl_xor(t, 2);
        t += __shfl_xor(t, 1);
        if (tid == 0) {
            const float log_const = logf(2.0f) - logf(0.3f) - 0.5f * logf(2.0f * (float)M_PI);
            out[0] = (float)NX * log_const - t * (1.0f / (2.0f * 0.3f * 0.3f));
        }
    }
}

extern "C" void kernel_launch(void* const* d_in, const int* in_sizes, int n_in,
                              void* d_out, int out_size, void* d_ws, size_t ws_size,
                              hipStream_t stream) {
    const float* ex = (const float*)d_in[0];
    const float* ey = (const float*)d_in[1];
    float* inv_nx        = (float*)d_ws;
    float* inv_ny        = inv_nx + NX;
    unsigned int* rowmax = (unsigned int*)(inv_ny + NY);
    float* out           = (float*)d_out;

    const size_t head = (size_t)(NX + NY + NX) * 4;          // norms + rowmax
    const size_t need = head + (size_t)(NX + NY) * KD;       // + i8 copies

    if (ws_size >= need) {
        char* exq = (char*)d_ws + head;
        char* eyq = exq + (size_t)NX * KD;
        convert_kernel<<<dim3((NX + NY) / 4), 256, 0, stream>>>(
            ex, ey, exq, eyq, inv_nx, inv_ny, rowmax);
        gemm_i8_kernel<<<dim3(NX / BM, NY / BN), 512, 0, stream>>>(
            exq, eyq, inv_ny, rowmax);
    } else {
        prep_kernel<<<dim3(NX / 4, 2), 256, 0, stream>>>(ex, ey, inv_nx, inv_ny, rowmax);
        gemmmax_f32_kernel<<<dim3(NX / 128, NY / 128), 256, 0, stream>>>(
            ex, ey, inv_ny, rowmax);
    }
    finalize_kernel<<<1, 1024, 0, stream>>>(rowmax, inv_nx, out);
}

// Round 16
// 64.116 us; speedup vs baseline: 1.8640x; 1.8640x over previous
//
#include <hip/hip_runtime.h>
#include <hip/hip_bf16.h>
#include <math.h>

typedef short short8  __attribute__((ext_vector_type(8)));
typedef float floatx4 __attribute__((ext_vector_type(4)));
typedef char  charx8  __attribute__((ext_vector_type(8)));
typedef int   intx4   __attribute__((ext_vector_type(4)));

#define NX 8192
#define NY 8192
#define KD 512
#define QS 26.0f                   // i8 quant scale
#define INV_QS2 (1.0f / (26.0f * 26.0f))
#define BM 128
#define BN 256
#define BK 64                      // bytes per row per K-tile (i8)

// ---- order-preserving float<->uint transform for atomicMax on floats ----
__device__ inline unsigned int f2u_ord(float x) {
    unsigned int u = __float_as_uint(x);
    return (u & 0x80000000u) ? ~u : (u | 0x80000000u);
}
__device__ inline float u2f_ord(unsigned int u) {
    return (u & 0x80000000u) ? __uint_as_float(u & 0x7fffffffu)
                             : __uint_as_float(~u);
}

__device__ inline char q8(float x) {
    float xs = fmaxf(-127.0f, fminf(127.0f, x * QS));
    return (char)(int)rintf(xs);
}
__device__ inline charx8 qpack8(const float4 u, const float4 v) {
    charx8 r;
    r[0] = q8(u.x); r[1] = q8(u.y); r[2] = q8(u.z); r[3] = q8(u.w);
    r[4] = q8(v.x); r[5] = q8(v.y); r[6] = q8(v.z); r[7] = q8(v.w);
    return r;
}

__device__ __forceinline__ void gload_lds16(const void* g, void* l) {
    __builtin_amdgcn_global_load_lds(
        (const __attribute__((address_space(1))) unsigned int*)g,
        (__attribute__((address_space(3))) unsigned int*)l, 16, 0, 0);
}

// ================= kernel 0: f32 -> i8 quantize + inv-norms + rowmax init ===
__global__ __launch_bounds__(256) void convert_kernel(
    const float* __restrict__ ex, const float* __restrict__ ey,
    char* __restrict__ exq, char* __restrict__ eyq,
    float* __restrict__ inv_nx, float* __restrict__ inv_ny,
    unsigned int* __restrict__ rowmax_u) {
    const int tid  = threadIdx.x;
    const int wid  = tid >> 6, lane = tid & 63;
    const int gr   = blockIdx.x * 4 + wid;          // 0..16383

    const bool isx = (gr < NX);
    const int row  = isx ? gr : gr - NX;
    const float* src = isx ? ex : ey;
    char* dst        = isx ? exq : eyq;
    float* inv       = isx ? inv_nx : inv_ny;

    const float4* p = reinterpret_cast<const float4*>(src + (size_t)row * KD) + lane * 2;
    float4 v0 = p[0], v1 = p[1];
    *reinterpret_cast<charx8*>(dst + (size_t)row * KD + lane * 8) = qpack8(v0, v1);

    float s = v0.x*v0.x + v0.y*v0.y + v0.z*v0.z + v0.w*v0.w
            + v1.x*v1.x + v1.y*v1.y + v1.z*v1.z + v1.w*v1.w;
    #pragma unroll
    for (int off = 32; off; off >>= 1) s += __shfl_xor(s, off);
    if (lane == 0) {
        inv[row] = 1.0f / sqrtf(s);
        if (isx) rowmax_u[row] = 0u;    // below transform of any real float
    }
}

// ================= kernel 1: 128x256 i8 MFMA GEMM (BK=64, co-resident) ======
// Round-8 best-measured configuration (gemm 51.3 us, total 63.9 us).
// 8 waves (2M x 4N), per-wave 64x64 out = 4x4 tiles of 16x16 (acc = 64 regs).
// 48 KB dbuf LDS + 2 KB reduce -> 2 blocks/CU; __launch_bounds__(512,4)
// caps regs so 16 waves/CU co-reside and fill barrier stalls (m114).
// One vmcnt(0)+barrier per K-tile. This structure sits at the DS-pipe
// instruction roof (~128 ds_read_b128/CU/K-tile x ~12cyc ~= measured
// 1923 cyc/K-tile); r9/r12/r13/r14/r15 alternatives all measured worse.
__global__ __launch_bounds__(512, 4) void gemm_i8_kernel(
    const char* __restrict__ exq, const char* __restrict__ eyq,
    const float* __restrict__ inv_ny, unsigned int* __restrict__ rowmax_u) {
    __shared__ char As[2][BM * BK];   // 2 x 8 KB
    __shared__ char Bs[2][BN * BK];   // 2 x 16 KB
    __shared__ float red[BM][4];      // cross-wave-col row-max reduce

    const int tid   = threadIdx.x;
    const int lane  = tid & 63;
    const int wid   = tid >> 6;     // 0..7
    const int wr    = wid >> 2;     // 0..1 (M)
    const int wc    = wid & 3;      // 0..3 (N)
    const int g     = lane >> 4;    // 0..3
    const int rlane = lane & 15;
    const int m0    = blockIdx.x * BM;
    const int n0    = blockIdx.y * BN;

    // staging map: 512 threads x 16 B = 8 KB = 128 rows of 64 B per issue
    const int sr  = tid >> 2;              // 0..127 row within issue
    const int sc  = tid & 3;               // chunk 0..3
    const int scs = sc ^ ((sr >> 1) & 3);  // pre-swizzled global source chunk

    intx4 acc[4][4];
    #pragma unroll
    for (int i = 0; i < 4; i++)
        #pragma unroll
        for (int j = 0; j < 4; j++)
            acc[i][j] = (intx4){0, 0, 0, 0};

    const char* gA  = exq + (size_t)(m0 + sr) * KD + (scs << 4);
    const char* gB0 = eyq + (size_t)(n0 + sr) * KD + (scs << 4);
    const char* gB1 = gB0 + (size_t)128 * KD;

    auto stage = [&](int t) {
        const int b = t & 1;
        gload_lds16(gA  + (t << 6), &As[b][tid * 16]);
        gload_lds16(gB0 + (t << 6), &Bs[b][tid * 16]);
        gload_lds16(gB1 + (t << 6), &Bs[b][128 * BK + tid * 16]);
    };
    auto rd = [&](const char* base, int row, int gg) -> intx4 {
        return *reinterpret_cast<const intx4*>(
            base + row * BK + (((gg ^ ((row >> 1) & 3))) << 4));
    };

    stage(0);

    for (int t = 0; t < 8; ++t) {           // KD/BK = 8 K-tiles
        // boundary: own stages drained by every wave, then all waves agree
        asm volatile("s_waitcnt vmcnt(0)" ::: "memory");
        __builtin_amdgcn_s_barrier();
        asm volatile("" ::: "memory");

        const char* Ab = As[t & 1];
        const char* Bb = Bs[t & 1];
        intx4 af[4], bf[4];
        #pragma unroll
        for (int ai = 0; ai < 4; ai++)
            af[ai] = rd(Ab, wr * 64 + ai * 16 + rlane, g);
        #pragma unroll
        for (int ni = 0; ni < 4; ni++)
            bf[ni] = rd(Bb, wc * 64 + ni * 16 + rlane, g);

        if (t < 7) stage(t + 1);            // into buf (t+1)&1 — disjoint

        __builtin_amdgcn_s_setprio(1);
        #pragma unroll
        for (int ai = 0; ai < 4; ai++)
            #pragma unroll
            for (int ni = 0; ni < 4; ni++)
                acc[ai][ni] = __builtin_amdgcn_mfma_i32_16x16x64_i8(
                    af[ai], bf[ni], acc[ai][ni], 0, 0, 0);
        __builtin_amdgcn_s_setprio(0);
    }

    // ---- epilogue: per-row max over this block's 256 columns ----
    float iny[4];
    #pragma unroll
    for (int ni = 0; ni < 4; ni++)
        iny[ni] = inv_ny[n0 + wc * 64 + ni * 16 + rlane] * INV_QS2;

    #pragma unroll
    for (int ai = 0; ai < 4; ai++) {
        #pragma unroll
        for (int reg = 0; reg < 4; reg++) {
            float v = -INFINITY;
            #pragma unroll
            for (int ni = 0; ni < 4; ni++)
                v = fmaxf(v, (float)acc[ai][ni][reg] * iny[ni]);
            v = fmaxf(v, __shfl_xor(v, 1));
            v = fmaxf(v, __shfl_xor(v, 2));
            v = fmaxf(v, __shfl_xor(v, 4));
            v = fmaxf(v, __shfl_xor(v, 8));
            if (rlane == 0)
                red[wr * 64 + ai * 16 + g * 4 + reg][wc] = v;
        }
    }
    __syncthreads();
    if (tid < BM) {
        float m = fmaxf(fmaxf(red[tid][0], red[tid][1]),
                        fmaxf(red[tid][2], red[tid][3]));
        atomicMax(rowmax_u + m0 + tid, f2u_ord(m));
    }
}

// ================= fallback path (f32-direct, used only if ws too small) ====
__device__ inline short bfbits(float x) {
    __hip_bfloat16 h = __float2bfloat16(x);
    return __builtin_bit_cast(short, h);
}
__device__ inline short8 pack8(const float4 u, const float4 v) {
    short8 r;
    r[0] = bfbits(u.x); r[1] = bfbits(u.y); r[2] = bfbits(u.z); r[3] = bfbits(u.w);
    r[4] = bfbits(v.x); r[5] = bfbits(v.y); r[6] = bfbits(v.z); r[7] = bfbits(v.w);
    return r;
}

__global__ __launch_bounds__(256) void prep_kernel(
    const float* __restrict__ ex, const float* __restrict__ ey,
    float* __restrict__ inv_nx, float* __restrict__ inv_ny,
    unsigned int* __restrict__ rowmax_u) {
    const int tid  = threadIdx.x;
    const int wave = tid >> 6, lane = tid & 63;
    const int row  = blockIdx.x * 4 + wave;
    if (blockIdx.y == 0) {
        int idx = blockIdx.x * 256 + tid;
        if (idx < NX) rowmax_u[idx] = 0u;
    }
    const float* src = (blockIdx.y == 0) ? ex : ey;
    float* dst       = (blockIdx.y == 0) ? inv_nx : inv_ny;
    const float4* p = reinterpret_cast<const float4*>(src + (size_t)row * KD) + lane * 2;
    float4 v0 = p[0], v1 = p[1];
    float s = v0.x*v0.x + v0.y*v0.y + v0.z*v0.z + v0.w*v0.w
            + v1.x*v1.x + v1.y*v1.y + v1.z*v1.z + v1.w*v1.w;
    #pragma unroll
    for (int off = 32; off; off >>= 1) s += __shfl_xor(s, off);
    if (lane == 0) dst[row] = 1.0f / sqrtf(s);
}

__global__ __launch_bounds__(256) void gemmmax_f32_kernel(
    const float* __restrict__ ex, const float* __restrict__ ey,
    const float* __restrict__ inv_ny, unsigned int* __restrict__ rowmax_u) {
    __shared__ short Asf[128 * 32];
    __shared__ short Bsf[128 * 32];
    const int tid  = threadIdx.x;
    const int lane = tid & 63;
    const int wid  = tid >> 6;
    const int wr   = wid >> 1, wc = wid & 1;
    const int m0   = blockIdx.x * 128;
    const int n0   = blockIdx.y * 128;
    const int srow = tid >> 1;
    const int sseg = tid & 1;
    const int sfz  = ((srow >> 1) & 3) << 4;

    floatx4 acc[4][4];
    #pragma unroll
    for (int mi = 0; mi < 4; mi++)
        #pragma unroll
        for (int ni = 0; ni < 4; ni++)
            acc[mi][ni] = (floatx4){0.f, 0.f, 0.f, 0.f};
    const int ksub  = lane >> 4;
    const int rlane = lane & 15;

    for (int k0 = 0; k0 < KD; k0 += 32) {
        const float4* ga = reinterpret_cast<const float4*>(
            ex + (size_t)(m0 + srow) * KD + k0 + sseg * 16);
        const float4* gb = reinterpret_cast<const float4*>(
            ey + (size_t)(n0 + srow) * KD + k0 + sseg * 16);
        float4 a0 = ga[0], a1 = ga[1], a2 = ga[2], a3 = ga[3];
        float4 b0 = gb[0], b1 = gb[1], b2 = gb[2], b3 = gb[3];
        __syncthreads();
        {
            char* ab = (char*)Asf + srow * 64;
            char* bb = (char*)Bsf + srow * 64;
            *reinterpret_cast<short8*>(ab + ((sseg * 32     ) ^ sfz)) = pack8(a0, a1);
            *reinterpret_cast<short8*>(ab + ((sseg * 32 + 16) ^ sfz)) = pack8(a2, a3);
            *reinterpret_cast<short8*>(bb + ((sseg * 32     ) ^ sfz)) = pack8(b0, b1);
            *reinterpret_cast<short8*>(bb + ((sseg * 32 + 16) ^ sfz)) = pack8(b2, b3);
        }
        __syncthreads();
        short8 afrag[4], bfrag[4];
        #pragma unroll
        for (int mi = 0; mi < 4; mi++) {
            int row = wr * 64 + mi * 16 + rlane;
            int fz  = ((row >> 1) & 3) << 4;
            afrag[mi] = *reinterpret_cast<const short8*>(
                (const char*)Asf + row * 64 + ((ksub * 16) ^ fz));
        }
        #pragma unroll
        for (int ni = 0; ni < 4; ni++) {
            int col = wc * 64 + ni * 16 + rlane;
            int fz  = ((col >> 1) & 3) << 4;
            bfrag[ni] = *reinterpret_cast<const short8*>(
                (const char*)Bsf + col * 64 + ((ksub * 16) ^ fz));
        }
        #pragma unroll
        for (int mi = 0; mi < 4; mi++)
            #pragma unroll
            for (int ni = 0; ni < 4; ni++)
                acc[mi][ni] = __builtin_amdgcn_mfma_f32_16x16x32_bf16(
                    afrag[mi], bfrag[ni], acc[mi][ni], 0, 0, 0);
    }
    float iny[4];
    #pragma unroll
    for (int ni = 0; ni < 4; ni++)
        iny[ni] = inv_ny[n0 + wc * 64 + ni * 16 + rlane];
    #pragma unroll
    for (int mi = 0; mi < 4; mi++) {
        #pragma unroll
        for (int reg = 0; reg < 4; reg++) {
            float v = -INFINITY;
            #pragma unroll
            for (int ni = 0; ni < 4; ni++)
                v = fmaxf(v, acc[mi][ni][reg] * iny[ni]);
            v = fmaxf(v, __shfl_xor(v, 1));
            v = fmaxf(v, __shfl_xor(v, 2));
            v = fmaxf(v, __shfl_xor(v, 4));
            v = fmaxf(v, __shfl_xor(v, 8));
            if (rlane == 0) {
                int row = m0 + wr * 64 + mi * 16 + ksub * 4 + reg;
                atomicMax(rowmax_u + row, f2u_ord(v));
            }
        }
    }
}

// ================= kernel 2: cmax -> HalfNormal log-prob -> sum =============
__global__ __launch_bounds__(1024) void finalize_kernel(
    const unsigned int* __restrict__ rowmax_u, const float* __restrict__ inv_nx,
    float* __restrict__ out) {
    __shared__ float red[16];
    const int tid = threadIdx.x;
    float s = 0.f;
    for (int i = tid; i < NX; i += 1024) {
        float cmax = u2f_ord(rowmax_u[i]) * inv_nx[i];
        float x = 1.0f - cmax;
        s += x * x;
    }
    #pragma unroll
    for (int off = 32; off; off >>= 1) s += __shfl_xor(s, off);
    if ((tid & 63) == 0) red[tid >> 6] = s;
    __syncthreads();
    if (tid < 16) {
        float t = red[tid];
        t += __shfl_xor(t, 8);
        t += __shfl_xor(t, 4);
        t += __shfl_xor(t, 2);
        t += __shfl_xor(t, 1);
        if (tid == 0) {
            const float log_const = logf(2.0f) - logf(0.3f) - 0.5f * logf(2.0f * (float)M_PI);
            out[0] = (float)NX * log_const - t * (1.0f / (2.0f * 0.3f * 0.3f));
        }
    }
}

extern "C" void kernel_launch(void* const* d_in, const int* in_sizes, int n_in,
                              void* d_out, int out_size, void* d_ws, size_t ws_size,
                              hipStream_t stream) {
    const float* ex = (const float*)d_in[0];
    const float* ey = (const float*)d_in[1];
    float* inv_nx        = (float*)d_ws;
    float* inv_ny        = inv_nx + NX;
    unsigned int* rowmax = (unsigned int*)(inv_ny + NY);
    float* out           = (float*)d_out;

    const size_t head = (size_t)(NX + NY + NX) * 4;          // norms + rowmax
    const size_t need = head + (size_t)(NX + NY) * KD;       // + i8 copies

    if (ws_size >= need) {
        char* exq = (char*)d_ws + head;
        char* eyq = exq + (size_t)NX * KD;
        convert_kernel<<<dim3((NX + NY) / 4), 256, 0, stream>>>(
            ex, ey, exq, eyq, inv_nx, inv_ny, rowmax);
        gemm_i8_kernel<<<dim3(NX / BM, NY / BN), 512, 0, stream>>>(
            exq, eyq, inv_ny, rowmax);
    } else {
        prep_kernel<<<dim3(NX / 4, 2), 256, 0, stream>>>(ex, ey, inv_nx, inv_ny, rowmax);
        gemmmax_f32_kernel<<<dim3(NX / 128, NY / 128), 256, 0, stream>>>(
            ex, ey, inv_ny, rowmax);
    }
    finalize_kernel<<<1, 1024, 0, stream>>>(rowmax, inv_nx, out);
}